// Round 6
// baseline (1598.300 us; speedup 1.0000x reference)
//
#include <hip/hip_runtime.h>
#include <cstdint>
#include <cstddef>

#define DIMX 256
#define DIMV 512
#define DIMH 768
#define EPSV 0.05f

typedef __bf16 bf16x8 __attribute__((ext_vector_type(8)));
typedef unsigned short u16x8 __attribute__((ext_vector_type(8)));
typedef unsigned int u32x4 __attribute__((ext_vector_type(4)));
typedef float f32x4 __attribute__((ext_vector_type(4)));

__device__ __forceinline__ unsigned short f2bf(float f) {
  unsigned int u = __float_as_uint(f);
  u += 0x7fffu + ((u >> 16) & 1u);
  return (unsigned short)(u >> 16);
}
__device__ __forceinline__ float bf2f(unsigned short b) {
  return __uint_as_float(((unsigned int)b) << 16);
}
__device__ __forceinline__ bf16x8 ld8(const unsigned short* p) {
  u16x8 u = *reinterpret_cast<const u16x8*>(p);
  return __builtin_bit_cast(bf16x8, u);
}
__device__ __forceinline__ f32x4 mfma16(bf16x8 a, bf16x8 b, f32x4 c) {
  return __builtin_amdgcn_mfma_f32_16x16x32_bf16(a, b, c, 0, 0, 0);
}

// ---------------- K0: split X into bf16 hi/lo for split-MFMA SYRK ----------------
__global__ void k_split(const float* __restrict__ X, unsigned short* __restrict__ Xhi,
                        unsigned short* __restrict__ Xlo) {
  int idx = blockIdx.x * 256 + threadIdx.x;
  if (idx < DIMH * DIMH) {
    float f = X[idx];
    unsigned short h = f2bf(f);
    Xhi[idx] = h;
    Xlo[idx] = f2bf(f - bf2f(h));
  }
}

// ---------------- K1: P = 0.5*Pstar@Pstar^T + eps*I (fp32, direct) ----------------
__global__ void k_syrkP(const float* __restrict__ A, float* __restrict__ P) {
  int bi = blockIdx.x >> 4, bj = blockIdx.x & 15;
  int ty = threadIdx.x >> 4, tx = threadIdx.x & 15;
  int i = bi * 16 + ty, j = bj * 16 + tx;
  const f32x4* ra = reinterpret_cast<const f32x4*>(A + (size_t)i * DIMX);
  const f32x4* rb = reinterpret_cast<const f32x4*>(A + (size_t)j * DIMX);
  float s = 0.f;
  for (int k = 0; k < 64; ++k) {
    f32x4 a = ra[k], b = rb[k];
    s = fmaf(a[0], b[0], s); s = fmaf(a[1], b[1], s);
    s = fmaf(a[2], b[2], s); s = fmaf(a[3], b[3], s);
  }
  P[(size_t)i * DIMX + j] = 0.5f * s + (i == j ? EPSV : 0.f);
}

// ---------------- K2: H = X@X^T + eps*I via bf16x2 split MFMA ----------------
__global__ __launch_bounds__(256) void k_syrkH(const unsigned short* __restrict__ Xhi,
                                               const unsigned short* __restrict__ Xlo,
                                               float* __restrict__ H) {
  int bx = blockIdx.x % 12, by = blockIdx.x / 12;
  int i0 = by * 64, j0 = bx * 64;
  int l = threadIdx.x & 63, wv = threadIdx.x >> 6;
  int lr = l & 15, lq = l >> 4;
  int koff = lq * 8;
  int arow = i0 + wv * 16 + lr;
  f32x4 z = {0.f, 0.f, 0.f, 0.f};
  f32x4 acc[4] = {z, z, z, z};
  for (int pass = 0; pass < 3; ++pass) {
    const unsigned short* Xa = (pass == 2) ? Xlo : Xhi;
    const unsigned short* Xb = (pass == 1) ? Xlo : Xhi;
    for (int kc = 0; kc < 24; ++kc) {
      bf16x8 a = ld8(&Xa[(size_t)arow * DIMH + kc * 32 + koff]);
#pragma unroll
      for (int ct = 0; ct < 4; ++ct) {
        bf16x8 b = ld8(&Xb[(size_t)(j0 + ct * 16 + lr) * DIMH + kc * 32 + koff]);
        acc[ct] = mfma16(a, b, acc[ct]);
      }
    }
  }
#pragma unroll
  for (int ct = 0; ct < 4; ++ct)
#pragma unroll
    for (int r = 0; r < 4; ++r) {
      int i = i0 + wv * 16 + lq * 4 + r;
      int j = j0 + ct * 16 + lr;
      H[(size_t)i * DIMH + j] = acc[ct][r] + (i == j ? EPSV : 0.f);
    }
}

// ---------------- K3: in-place blocked Cholesky of P (replaces Gauss-Jordan) -------
// P symmetric -> row-major buffer doubles as col-major A[i][j] = buf[j*256+i].
// L overwrites the lower triangle. Panel rows factor in per-thread REGISTERS with the
// 32-col loop FULLY UNROLLED (static rr[] indices; rounds 4/5 showed dynamic/large
// register state => allocator spills). Trailing SYRK uses LDS PanT with per-lane-
// distinct b128 reads + 4x4 register tiles over LOWER tiles only. Upper triangle
// holds garbage throughout but is provably never read.
__global__ __launch_bounds__(256, 2) void k_chol(float* __restrict__ A) {
  __shared__ float PanT[32][260];
  __shared__ __align__(16) float vk[32];
  __shared__ float ipS;
  int p = threadIdx.x;
#pragma unroll 1
  for (int s = 0; s < 8; ++s) {
    int K = 32 * s, R = 256 - K;
    bool act = p < R;
    float rr[32];
    if (act) {
#pragma unroll
      for (int c = 0; c < 32; ++c) rr[c] = A[(K + c) * 256 + K + p];
    }
    // panel factor: 32 columns, fully unrolled (all rr indices static)
#pragma unroll
    for (int k = 0; k < 32; ++k) {
      if (p == k) ipS = rsqrtf(rr[k]);
      __syncthreads();
      float ip = ipS;
      if (act && p >= k) {
        float v = rr[k] * ip;
        rr[k] = v;
        if (p > k && p < 32) vk[p] = v;
      }
      __syncthreads();
      if (act && p > k) {
        float v = rr[k];
#pragma unroll
        for (int g = 0; g < 8; ++g) {
          if (4 * g + 3 > k) {
            f32x4 vq = *reinterpret_cast<const f32x4*>(&vk[4 * g]);
#pragma unroll
            for (int e = 0; e < 4; ++e) {
              if (4 * g + e > k) rr[4 * g + e] = fmaf(-v, vq[e], rr[4 * g + e]);
            }
          }
        }
      }
    }
    __syncthreads();
    // write back panel (global + LDS PanT for the SYRK)
    if (act) {
#pragma unroll
      for (int c = 0; c < 32; ++c) {
        A[(K + c) * 256 + K + p] = rr[c];
        PanT[c][p] = rr[c];
      }
    }
    __syncthreads();
    // trailing SYRK: A[i][j] -= sum_k L[i][K+k]*L[j][K+k], lower 4x4 tiles only
    int T = R - 32;
    if (T > 0) {
      int T4 = T >> 2;
      int ntile = T4 * (T4 + 1) / 2;
      for (int idx = p; idx < ntile; idx += 256) {
        int ti = (int)((sqrtf(8.0f * (float)idx + 1.0f) - 1.0f) * 0.5f);
        while ((ti + 1) * (ti + 2) / 2 <= idx) ++ti;
        while (ti * (ti + 1) / 2 > idx) --ti;
        int tj = idx - ti * (ti + 1) / 2;
        int i0 = K + 32 + 4 * ti, j0 = K + 32 + 4 * tj;
        int ri = 32 + 4 * ti, rj = 32 + 4 * tj;
        f32x4 acc[4];
#pragma unroll
        for (int jj = 0; jj < 4; ++jj)
          acc[jj] = *reinterpret_cast<const f32x4*>(&A[(j0 + jj) * 256 + i0]);
#pragma unroll
        for (int k = 0; k < 32; ++k) {
          f32x4 av = *reinterpret_cast<const f32x4*>(&PanT[k][ri]);
          f32x4 bv = *reinterpret_cast<const f32x4*>(&PanT[k][rj]);
#pragma unroll
          for (int jj = 0; jj < 4; ++jj) {
            acc[jj][0] = fmaf(-av[0], bv[jj], acc[jj][0]);
            acc[jj][1] = fmaf(-av[1], bv[jj], acc[jj][1]);
            acc[jj][2] = fmaf(-av[2], bv[jj], acc[jj][2]);
            acc[jj][3] = fmaf(-av[3], bv[jj], acc[jj][3]);
          }
        }
#pragma unroll
        for (int jj = 0; jj < 4; ++jj)
          *reinterpret_cast<f32x4*>(&A[(j0 + jj) * 256 + i0]) = acc[jj];
      }
    }
    __syncthreads();
  }
}

// ---------------- K4: Gin[c][q] = [C1 | D11] as bf16 ----------------
__global__ void k_gin(const float* __restrict__ H, const float* __restrict__ Chi,
                      unsigned short* __restrict__ Gin) {
  int q = blockIdx.x * 256 + threadIdx.x;
  int c = blockIdx.y;
  float rlam = 2.f / H[(size_t)(256 + c) * DIMH + 256 + c];
  float v;
  if (q < 256) {
    v = Chi[(size_t)q * DIMV + c] * rlam;
  } else {
    int j = q - 256;
    v = (j < c) ? -H[(size_t)(256 + c) * DIMH + 256 + j] * rlam : 0.f;
  }
  Gin[(size_t)c * DIMH + q] = f2bf(v);
}

// ---------------- K5: Gout = P^{-1} [Y|M] via Cholesky solve (replaces k_gout) -----
// 24 blocks x 32 RHS columns. B built on the fly into LDS; blocked fwd/bwd
// triangular solve; micro-solves fully static-unrolled on 32 lanes (z in regs);
// rank-32 GEMM updates with coalesced col-major L reads. L = lower(A) col-major:
// L[i][j] = Lg[j*256+i].
__global__ __launch_bounds__(256, 2) void k_gsolve(const float* __restrict__ Lg,
                                                   const float* __restrict__ H,
                                                   const float* __restrict__ Y1,
                                                   const float* __restrict__ Chi,
                                                   unsigned short* __restrict__ Gout) {
  __shared__ float Bs[256][33];
  __shared__ float Ld[32][36];
  int t = threadIdx.x, tc = t & 31, rg = t >> 5;
  int q0 = blockIdx.x * 32, q = q0 + tc;
  // build B = [Y | M] columns q0..q0+31
#pragma unroll 1
  for (int rr = 0; rr < 32; ++rr) {
    int r = rg * 32 + rr;
    float v;
    if (q < 256) {
      v = -0.5f * (H[(size_t)r * DIMH + q] + Y1[r * 256 + q] - Y1[q * 256 + r]);
    } else {
      int c = q - 256;
      v = -(H[(size_t)r * DIMH + 256 + c] + Chi[r * 512 + c]);
    }
    Bs[r][tc] = v;
  }
  __syncthreads();
  // forward solve: L u = B
#pragma unroll 1
  for (int tb = 0; tb < 8; ++tb) {
    {
      int j = rg * 4;
#pragma unroll
      for (int jj = 0; jj < 4; ++jj)
        Ld[tc][j + jj] = Lg[(32 * tb + j + jj) * 256 + 32 * tb + tc];
    }
    __syncthreads();
    if (t < 32) {
      float z[32];
#pragma unroll
      for (int i = 0; i < 32; ++i) {
        float acc = Bs[32 * tb + i][t];
#pragma unroll
        for (int g = 0; g < 8; ++g) {
          if (4 * g < i) {
            f32x4 lv = *reinterpret_cast<const f32x4*>(&Ld[i][4 * g]);
#pragma unroll
            for (int e = 0; e < 4; ++e)
              if (4 * g + e < i) acc = fmaf(-lv[e], z[4 * g + e], acc);
          }
        }
        z[i] = acc / Ld[i][i];
      }
#pragma unroll
      for (int i = 0; i < 32; ++i) Bs[32 * tb + i][t] = z[i];
    }
    __syncthreads();
    if (tb < 7) {
      float zz[32];
#pragma unroll
      for (int k = 0; k < 32; ++k) zz[k] = Bs[32 * tb + k][tc];
      int r0full = 32 * (tb + 1);
      int nr4 = (256 - r0full) >> 2;
      for (int g = rg; g < nr4; g += 8) {
        int r = r0full + 4 * g;
        f32x4 acc = {Bs[r][tc], Bs[r + 1][tc], Bs[r + 2][tc], Bs[r + 3][tc]};
#pragma unroll
        for (int k = 0; k < 32; ++k) {
          f32x4 lv = *reinterpret_cast<const f32x4*>(&Lg[(32 * tb + k) * 256 + r]);
          acc[0] = fmaf(-lv[0], zz[k], acc[0]);
          acc[1] = fmaf(-lv[1], zz[k], acc[1]);
          acc[2] = fmaf(-lv[2], zz[k], acc[2]);
          acc[3] = fmaf(-lv[3], zz[k], acc[3]);
        }
        Bs[r][tc] = acc[0]; Bs[r + 1][tc] = acc[1];
        Bs[r + 2][tc] = acc[2]; Bs[r + 3][tc] = acc[3];
      }
      __syncthreads();
    }
  }
  // backward solve: L^T g = u   (U[i][j] = L[j][i])
#pragma unroll 1
  for (int tb = 7; tb >= 0; --tb) {
    {
      int j = rg * 4;
#pragma unroll
      for (int jj = 0; jj < 4; ++jj)
        Ld[tc][j + jj] = Lg[(32 * tb + tc) * 256 + 32 * tb + j + jj];
    }
    __syncthreads();
    if (t < 32) {
      float z[32];
#pragma unroll
      for (int ii = 0; ii < 32; ++ii) {
        int i = 31 - ii;
        float acc = Bs[32 * tb + i][t];
#pragma unroll
        for (int g = 0; g < 8; ++g) {
          if (4 * g + 3 > i) {
            f32x4 lv = *reinterpret_cast<const f32x4*>(&Ld[i][4 * g]);
#pragma unroll
            for (int e = 0; e < 4; ++e)
              if (4 * g + e > i) acc = fmaf(-lv[e], z[4 * g + e], acc);
          }
        }
        z[i] = acc / Ld[i][i];
      }
#pragma unroll
      for (int i = 0; i < 32; ++i) Bs[32 * tb + i][t] = z[i];
    }
    __syncthreads();
    if (tb > 0) {
      float zz[32];
#pragma unroll
      for (int k = 0; k < 32; ++k) zz[k] = Bs[32 * tb + k][tc];
      int nr4 = (32 * tb) >> 2;
      for (int g = rg; g < nr4; g += 8) {
        int r = 4 * g;
        f32x4 acc = {Bs[r][tc], Bs[r + 1][tc], Bs[r + 2][tc], Bs[r + 3][tc]};
#pragma unroll
        for (int kq = 0; kq < 8; ++kq) {
          f32x4 l0 = *reinterpret_cast<const f32x4*>(&Lg[(r + 0) * 256 + 32 * tb + 4 * kq]);
          f32x4 l1 = *reinterpret_cast<const f32x4*>(&Lg[(r + 1) * 256 + 32 * tb + 4 * kq]);
          f32x4 l2 = *reinterpret_cast<const f32x4*>(&Lg[(r + 2) * 256 + 32 * tb + 4 * kq]);
          f32x4 l3 = *reinterpret_cast<const f32x4*>(&Lg[(r + 3) * 256 + 32 * tb + 4 * kq]);
#pragma unroll
          for (int e = 0; e < 4; ++e) {
            float zv = zz[4 * kq + e];
            acc[0] = fmaf(-l0[e], zv, acc[0]);
            acc[1] = fmaf(-l1[e], zv, acc[1]);
            acc[2] = fmaf(-l2[e], zv, acc[2]);
            acc[3] = fmaf(-l3[e], zv, acc[3]);
          }
        }
        Bs[r][tc] = acc[0]; Bs[r + 1][tc] = acc[1];
        Bs[r + 2][tc] = acc[2]; Bs[r + 3][tc] = acc[3];
      }
      __syncthreads();
    }
  }
  // write Gout bf16 (row-major [256][768])
#pragma unroll 1
  for (int rr = 0; rr < 32; ++rr) {
    int r = rg * 32 + rr;
    Gout[(size_t)r * DIMH + q] = f2bf(Bs[r][tc]);
  }
}

// ---------------- K6: fused main v3 — [x|w] A-operand entirely in registers ----------------
// (unchanged this round: counters surface next profile as top dispatch)
#define ACCSTR 33
#define ACC_W 4224
#define DD_W 2048
#define WT_W 2560
#define SMEM_MAIN (4 * (ACC_W + DD_W + WT_W))

__global__ __launch_bounds__(256, 2) void k_main(const float* __restrict__ x,
                                                 const unsigned short* __restrict__ Gin,
                                                 const unsigned short* __restrict__ Gout,
                                                 const float* __restrict__ bv,
                                                 const float* __restrict__ bx,
                                                 float* __restrict__ out) {
  extern __shared__ char smem[];
  int tid = threadIdx.x;
  int wv = tid >> 6, l = tid & 63;
  int lr = l & 15, lq = l >> 4, koff = lq * 8;
  float* accb = (float*)(smem + wv * ACC_W);
  char* ddiag = smem + 4 * ACC_W + wv * DD_W;
  char* wtmp = smem + 4 * ACC_W + 4 * DD_W + wv * WT_W;

  int rowbase = blockIdx.x * 128 + wv * 32;

  bf16x8 frag0[24], frag1[24];
  {
    u16x8 zz = {0, 0, 0, 0, 0, 0, 0, 0};
#pragma unroll
    for (int c = 8; c < 24; ++c) {
      frag0[c] = __builtin_bit_cast(bf16x8, zz);
      frag1[c] = __builtin_bit_cast(bf16x8, zz);
    }
  }
#pragma unroll
  for (int kc = 0; kc < 8; ++kc) {
    const float* xr0 = x + (size_t)(rowbase + lr) * 256 + koff + kc * 32;
    const float* xr1 = x + (size_t)(rowbase + 16 + lr) * 256 + koff + kc * 32;
    f32x4 a0 = *reinterpret_cast<const f32x4*>(xr0);
    f32x4 a1 = *reinterpret_cast<const f32x4*>(xr0 + 4);
    f32x4 b0 = *reinterpret_cast<const f32x4*>(xr1);
    f32x4 b1 = *reinterpret_cast<const f32x4*>(xr1 + 4);
    u16x8 u0, u1;
#pragma unroll
    for (int e = 0; e < 4; ++e) {
      u0[e] = f2bf(a0[e]); u0[4 + e] = f2bf(a1[e]);
      u1[e] = f2bf(b0[e]); u1[4 + e] = f2bf(b1[e]);
    }
    frag0[kc] = __builtin_bit_cast(bf16x8, u0);
    frag1[kc] = __builtin_bit_cast(bf16x8, u1);
  }

  f32x4 z = {0.f, 0.f, 0.f, 0.f};

#pragma unroll 1
  for (int b = 0; b < 16; ++b) {
#pragma unroll
    for (int t = 0; t < 2; ++t) {
      int row = t * 16 + (l >> 2);
      const unsigned short* src =
          Gin + (size_t)(32 * b + row) * DIMH + 256 + 32 * b + (l & 3) * 8;
      u16x8 v = *reinterpret_cast<const u16x8*>(src);
      *reinterpret_cast<u16x8*>(ddiag + t * 1024 + l * 16) = v;
    }

    f32x4 a00 = z, a01 = z, a10 = z, a11 = z;
    const unsigned short* gb0 = Gin + (size_t)(32 * b + lr) * DIMH + koff;
    const unsigned short* gb1 = gb0 + 16 * DIMH;
#pragma unroll
    for (int g = 0; g < 6; ++g) {
      if (g * 4 < 8 + b) {
#pragma unroll
        for (int cc = 0; cc < 4; ++cc) {
          int c = g * 4 + cc;
          bf16x8 bb0 = ld8(gb0 + c * 32);
          bf16x8 bb1 = ld8(gb1 + c * 32);
          a00 = mfma16(frag0[c], bb0, a00);
          a01 = mfma16(frag0[c], bb1, a01);
          a10 = mfma16(frag1[c], bb0, a10);
          a11 = mfma16(frag1[c], bb1, a11);
        }
      }
    }

    float bv0 = bv[32 * b + lr], bv1 = bv[32 * b + 16 + lr];
#pragma unroll
    for (int r = 0; r < 4; ++r) {
      accb[(lq * 4 + r) * ACCSTR + lr] = a00[r] + bv0;
      accb[(lq * 4 + r) * ACCSTR + 16 + lr] = a01[r] + bv1;
      accb[(16 + lq * 4 + r) * ACCSTR + lr] = a10[r] + bv0;
      accb[(16 + lq * 4 + r) * ACCSTR + 16 + lr] = a11[r] + bv1;
    }

    if (l < 32) {
      const unsigned int* dd = (const unsigned int*)ddiag;
      float wf[32];
      unsigned int wpk[16];
#pragma unroll
      for (int i = 0; i < 32; ++i) {
        float p0 = 0.f, p1 = 0.f;
        const unsigned int* ddr = dd + i * 16;
#pragma unroll
        for (int j = 0; j < i; ++j) {
          unsigned int pw = ddr[j >> 1];
          float dj = __uint_as_float((j & 1) ? (pw & 0xffff0000u) : (pw << 16));
          if (j & 1) p1 = fmaf(dj, wf[j], p1);
          else       p0 = fmaf(dj, wf[j], p0);
        }
        float s = accb[l * ACCSTR + i] + p0 + p1;
        s = fminf(fmaxf(s, -12.f), 12.f);
        float e = __expf(2.f * s);
        float w = (e - 1.f) * __builtin_amdgcn_rcpf(e + 1.f);
        wf[i] = w;
        unsigned int hb = (unsigned int)f2bf(w);
        if (i & 1) wpk[i >> 1] |= hb << 16;
        else       wpk[i >> 1] = hb;
      }
      u32x4* wp = (u32x4*)(wtmp + l * 80);
      u32x4 w0 = {wpk[0], wpk[1], wpk[2], wpk[3]};     wp[0] = w0;
      u32x4 w1 = {wpk[4], wpk[5], wpk[6], wpk[7]};     wp[1] = w1;
      u32x4 w2 = {wpk[8], wpk[9], wpk[10], wpk[11]};   wp[2] = w2;
      u32x4 w3 = {wpk[12], wpk[13], wpk[14], wpk[15]}; wp[3] = w3;
    }

    bf16x8 nw0 = ld8((const unsigned short*)(wtmp + lr * 80 + lq * 16));
    bf16x8 nw1 = ld8((const unsigned short*)(wtmp + (16 + lr) * 80 + lq * 16));
#pragma unroll
    for (int j = 0; j < 16; ++j) {
      if (b == j) { frag0[8 + j] = nw0; frag1[8 + j] = nw1; }
    }
  }

#pragma unroll 1
  for (int ct = 0; ct < 16; ++ct) {
    f32x4 o0 = z, o1 = z;
    const unsigned short* gg = Gout + (size_t)(ct * 16 + lr) * DIMH + koff;
#pragma unroll
    for (int c = 0; c < 24; ++c) {
      bf16x8 bb = ld8(gg + c * 32);
      o0 = mfma16(frag0[c], bb, o0);
      o1 = mfma16(frag1[c], bb, o1);
    }
    float bxv = bx[ct * 16 + lr];
#pragma unroll
    for (int r = 0; r < 4; ++r) {
      out[(size_t)(rowbase + lq * 4 + r) * 256 + ct * 16 + lr] = o0[r] + bxv;
      out[(size_t)(rowbase + 16 + lq * 4 + r) * 256 + ct * 16 + lr] = o1[r] + bxv;
    }
  }
}

extern "C" void kernel_launch(void* const* d_in, const int* in_sizes, int n_in,
                              void* d_out, int out_size, void* d_ws, size_t ws_size,
                              hipStream_t stream) {
  const float* x   = (const float*)d_in[1];
  const float* Pst = (const float*)d_in[2];
  const float* Chi = (const float*)d_in[3];
  const float* X   = (const float*)d_in[4];
  const float* Y1  = (const float*)d_in[5];
  const float* bv  = (const float*)d_in[8];
  const float* bx  = (const float*)d_in[9];
  float* out = (float*)d_out;

  char* ws = (char*)d_ws;
  const size_t OFF_H    = 0;
  const size_t OFF_P    = 2359296;
  const size_t OFF_XHI  = 2883584;
  const size_t OFF_XLO  = 4063232;
  const size_t OFF_GIN  = 5242880;
  const size_t OFF_GOUT = 6029312;
  if (ws_size < 6422528) return;

  float* H    = (float*)(ws + OFF_H);
  float* P    = (float*)(ws + OFF_P);   // becomes L (lower, col-major) after k_chol
  unsigned short* Xhi  = (unsigned short*)(ws + OFF_XHI);
  unsigned short* Xlo  = (unsigned short*)(ws + OFF_XLO);
  unsigned short* Gin  = (unsigned short*)(ws + OFF_GIN);
  unsigned short* Gout = (unsigned short*)(ws + OFF_GOUT);

  k_split<<<2304, 256, 0, stream>>>(X, Xhi, Xlo);
  k_syrkP<<<256, 256, 0, stream>>>(Pst, P);
  k_chol<<<1, 256, 0, stream>>>(P);
  k_syrkH<<<144, 256, 0, stream>>>(Xhi, Xlo, H);
  dim3 gg(3, 512);
  k_gin<<<gg, 256, 0, stream>>>(H, Chi, Gin);
  k_gsolve<<<24, 256, 0, stream>>>(P, H, Y1, Chi, Gout);
  k_main<<<512, 256, SMEM_MAIN, stream>>>(x, Gin, Gout, bv, bx, out);
}

// Round 7
// 1335.687 us; speedup vs baseline: 1.1966x; 1.1966x over previous
//
#include <hip/hip_runtime.h>
#include <cstdint>
#include <cstddef>

#define DIMX 256
#define DIMV 512
#define DIMH 768
#define EPSV 0.05f

typedef __bf16 bf16x8 __attribute__((ext_vector_type(8)));
typedef unsigned short u16x8 __attribute__((ext_vector_type(8)));
typedef unsigned int u32x4 __attribute__((ext_vector_type(4)));
typedef float f32x4 __attribute__((ext_vector_type(4)));

__device__ __forceinline__ unsigned short f2bf(float f) {
  unsigned int u = __float_as_uint(f);
  u += 0x7fffu + ((u >> 16) & 1u);
  return (unsigned short)(u >> 16);
}
__device__ __forceinline__ float bf2f(unsigned short b) {
  return __uint_as_float(((unsigned int)b) << 16);
}
__device__ __forceinline__ bf16x8 ld8(const unsigned short* p) {
  u16x8 u = *reinterpret_cast<const u16x8*>(p);
  return __builtin_bit_cast(bf16x8, u);
}
__device__ __forceinline__ f32x4 mfma16(bf16x8 a, bf16x8 b, f32x4 c) {
  return __builtin_amdgcn_mfma_f32_16x16x32_bf16(a, b, c, 0, 0, 0);
}
__device__ __forceinline__ float rdlane(float v, int lane) {
  return __uint_as_float(
      (unsigned int)__builtin_amdgcn_readlane((int)__float_as_uint(v), lane));
}

// ---------------- K0: split X into bf16 hi/lo for split-MFMA SYRK ----------------
__global__ void k_split(const float* __restrict__ X, unsigned short* __restrict__ Xhi,
                        unsigned short* __restrict__ Xlo) {
  int idx = blockIdx.x * 256 + threadIdx.x;
  if (idx < DIMH * DIMH) {
    float f = X[idx];
    unsigned short h = f2bf(f);
    Xhi[idx] = h;
    Xlo[idx] = f2bf(f - bf2f(h));
  }
}

// ---------------- K1: P = 0.5*Pstar@Pstar^T + eps*I (fp32, direct) ----------------
__global__ void k_syrkP(const float* __restrict__ A, float* __restrict__ P) {
  int bi = blockIdx.x >> 4, bj = blockIdx.x & 15;
  int ty = threadIdx.x >> 4, tx = threadIdx.x & 15;
  int i = bi * 16 + ty, j = bj * 16 + tx;
  const f32x4* ra = reinterpret_cast<const f32x4*>(A + (size_t)i * DIMX);
  const f32x4* rb = reinterpret_cast<const f32x4*>(A + (size_t)j * DIMX);
  float s = 0.f;
  for (int k = 0; k < 64; ++k) {
    f32x4 a = ra[k], b = rb[k];
    s = fmaf(a[0], b[0], s); s = fmaf(a[1], b[1], s);
    s = fmaf(a[2], b[2], s); s = fmaf(a[3], b[3], s);
  }
  P[(size_t)i * DIMX + j] = 0.5f * s + (i == j ? EPSV : 0.f);
}

// ---------------- K2: H = X@X^T + eps*I via bf16x2 split MFMA ----------------
__global__ __launch_bounds__(256) void k_syrkH(const unsigned short* __restrict__ Xhi,
                                               const unsigned short* __restrict__ Xlo,
                                               float* __restrict__ H) {
  int bx = blockIdx.x % 12, by = blockIdx.x / 12;
  int i0 = by * 64, j0 = bx * 64;
  int l = threadIdx.x & 63, wv = threadIdx.x >> 6;
  int lr = l & 15, lq = l >> 4;
  int koff = lq * 8;
  int arow = i0 + wv * 16 + lr;
  f32x4 z = {0.f, 0.f, 0.f, 0.f};
  f32x4 acc[4] = {z, z, z, z};
  for (int pass = 0; pass < 3; ++pass) {
    const unsigned short* Xa = (pass == 2) ? Xlo : Xhi;
    const unsigned short* Xb = (pass == 1) ? Xlo : Xhi;
    for (int kc = 0; kc < 24; ++kc) {
      bf16x8 a = ld8(&Xa[(size_t)arow * DIMH + kc * 32 + koff]);
#pragma unroll
      for (int ct = 0; ct < 4; ++ct) {
        bf16x8 b = ld8(&Xb[(size_t)(j0 + ct * 16 + lr) * DIMH + kc * 32 + koff]);
        acc[ct] = mfma16(a, b, acc[ct]);
      }
    }
  }
#pragma unroll
  for (int ct = 0; ct < 4; ++ct)
#pragma unroll
    for (int r = 0; r < 4; ++r) {
      int i = i0 + wv * 16 + lq * 4 + r;
      int j = j0 + ct * 16 + lr;
      H[(size_t)i * DIMH + j] = acc[ct][r] + (i == j ? EPSV : 0.f);
    }
}

// ---------------- K3: blocked Cholesky; serial 32x32 work on ONE WAVE in registers -----
// Matrix col-major in-place: A[i][j] = buf[j*256+i]; L overwrites lower triangle.
// Per 32-step s: wave0 factors D (lane=row, readlane broadcasts, fully unrolled) and
// computes W=Ld^{-1} (lane=col) — ~1060 readlane+fma total, NO barriers/LDS in the chain
// (rounds 4-6: barrier-per-microstep costs 3.5-8.8K cyc/step -> 437-937us).
// Then all 16 waves: TRSM L21=A21*W^T into LDS T; copy T->global; SYRK trailing update.
__global__ __launch_bounds__(1024) void k_chol(float* __restrict__ A,
                                               float* __restrict__ Wbuf) {
  __shared__ float Wl[32][33];    // W row-major: Wl[r][k] = W[r][k]
  __shared__ float T[32][232];    // T[j][rloc] = L21[rloc][j]
  int t = threadIdx.x;
  int wv = t >> 6, l = t & 63;
#pragma unroll 1
  for (int s = 0; s < 8; ++s) {
    int K = 32 * s;
    int R32 = 256 - K - 32;  // trailing rows (224,192,...,0)
    if (wv == 0) {
      int li = l & 31;
      float d[32];
#pragma unroll
      for (int j = 0; j < 32; ++j) d[j] = A[(K + j) * 256 + K + li];
      // pass A: Cholesky, lane i = row i. Upper-triangle regs hold garbage; every
      // readlane(d[k], j) has k<j (lower) or k==j (diag) -> garbage never read.
#pragma unroll
      for (int k = 0; k < 32; ++k) {
        float dkk = rdlane(d[k], k);
        float ip = rsqrtf(dkk);
        d[k] *= ip;  // L[i][k] for i>=k
#pragma unroll
        for (int j = k + 1; j < 32; ++j) {
          float ljk = rdlane(d[k], j);
          d[j] = fmaf(-ljk, d[k], d[j]);
        }
      }
      // pass B: W = Ld^{-1}, lane j = column j. wcol[k] = W[k][j].
      float wcol[32];
#pragma unroll
      for (int i = 0; i < 32; ++i) {
        float Lii = rdlane(d[i], i);
        float ipi = 1.0f / Lii;
        float acc = (li == i) ? 1.0f : 0.0f;
#pragma unroll
        for (int k = 0; k < i; ++k) {
          float Lik = rdlane(d[k], i);
          acc = fmaf(-Lik, wcol[k], acc);
        }
        wcol[i] = acc * ipi;  // stays 0 for j>i (upper) since acc=0
      }
      if (l < 32) {
#pragma unroll
        for (int k = 0; k < 32; ++k) {
          Wl[k][l] = wcol[k];                       // Wl[k][j] = W[k][j]
          Wbuf[s * 1024 + k * 32 + l] = wcol[k];    // row-major W for k_gsolve
        }
      }
    }
    __syncthreads();
    if (R32 > 0) {
      // TRSM: L21[r][j] = sum_k A21[r][k] * W[j][k]  -> write into LDS T only
      int nrt = R32 >> 2;  // 4-row tiles
      for (int u = t; u < nrt * 8; u += 1024) {
        int rt = u >> 3, jg = u & 7;
        int r = K + 32 + rt * 4;
        int j0 = jg * 4;
        f32x4 z4 = {0.f, 0.f, 0.f, 0.f};
        f32x4 acc[4] = {z4, z4, z4, z4};
#pragma unroll
        for (int k = 0; k < 32; ++k) {
          f32x4 av = *reinterpret_cast<const f32x4*>(&A[(K + k) * 256 + r]);
#pragma unroll
          for (int jj = 0; jj < 4; ++jj) {
            float w = Wl[j0 + jj][k];
            acc[jj][0] = fmaf(av[0], w, acc[jj][0]);
            acc[jj][1] = fmaf(av[1], w, acc[jj][1]);
            acc[jj][2] = fmaf(av[2], w, acc[jj][2]);
            acc[jj][3] = fmaf(av[3], w, acc[jj][3]);
          }
        }
#pragma unroll
        for (int jj = 0; jj < 4; ++jj)
          *reinterpret_cast<f32x4*>(&T[j0 + jj][rt * 4]) = acc[jj];
      }
      __syncthreads();
      // copy T -> global A21 (L21 in place), coalesced per column
#pragma unroll 1
      for (int j = 0; j < 32; ++j) {
        int rl = t << 2;
        if (rl < R32)
          *reinterpret_cast<f32x4*>(&A[(K + j) * 256 + K + 32 + rl]) =
              *reinterpret_cast<const f32x4*>(&T[j][rl]);
      }
      // SYRK: A22 -= L21 L21^T, lower 4x4 tiles (each tile owned by one thread)
      int T4 = R32 >> 2;
      int ntile = T4 * (T4 + 1) / 2;
      for (int idx = t; idx < ntile; idx += 1024) {
        int ti = (int)((sqrtf(8.0f * (float)idx + 1.0f) - 1.0f) * 0.5f);
        while ((ti + 1) * (ti + 2) / 2 <= idx) ++ti;
        while (ti * (ti + 1) / 2 > idx) --ti;
        int tj = idx - ti * (ti + 1) / 2;
        int gi = K + 32 + 4 * ti, gj = K + 32 + 4 * tj;
        f32x4 acc[4];
#pragma unroll
        for (int jj = 0; jj < 4; ++jj)
          acc[jj] = *reinterpret_cast<const f32x4*>(&A[(gj + jj) * 256 + gi]);
#pragma unroll
        for (int k = 0; k < 32; ++k) {
          f32x4 av = *reinterpret_cast<const f32x4*>(&T[k][4 * ti]);
          f32x4 bv = *reinterpret_cast<const f32x4*>(&T[k][4 * tj]);
#pragma unroll
          for (int jj = 0; jj < 4; ++jj) {
            acc[jj][0] = fmaf(-av[0], bv[jj], acc[jj][0]);
            acc[jj][1] = fmaf(-av[1], bv[jj], acc[jj][1]);
            acc[jj][2] = fmaf(-av[2], bv[jj], acc[jj][2]);
            acc[jj][3] = fmaf(-av[3], bv[jj], acc[jj][3]);
          }
        }
#pragma unroll
        for (int jj = 0; jj < 4; ++jj)
          *reinterpret_cast<f32x4*>(&A[(gj + jj) * 256 + gi]) = acc[jj];
      }
    }
    __syncthreads();
  }
}

// ---------------- K4: Gin[c][q] = [C1 | D11] as bf16 ----------------
__global__ void k_gin(const float* __restrict__ H, const float* __restrict__ Chi,
                      unsigned short* __restrict__ Gin) {
  int q = blockIdx.x * 256 + threadIdx.x;
  int c = blockIdx.y;
  float rlam = 2.f / H[(size_t)(256 + c) * DIMH + 256 + c];
  float v;
  if (q < 256) {
    v = Chi[(size_t)q * DIMV + c] * rlam;
  } else {
    int j = q - 256;
    v = (j < c) ? -H[(size_t)(256 + c) * DIMH + 256 + j] * rlam : 0.f;
  }
  Gin[(size_t)c * DIMH + q] = f2bf(v);
}

// ---------------- K5: Gout = P^{-1}[Y|M] via BLOCK substitution (GEMM-only) --------
// Uses precomputed W_s = Ld_s^{-1}: 16 serial block-steps, no scalar divides
// (round-6 gsolve had 512 micro-steps with divides -> latency-bound).
__global__ __launch_bounds__(256, 2) void k_gsolve(const float* __restrict__ Lg,
                                                   const float* __restrict__ Wbuf,
                                                   const float* __restrict__ H,
                                                   const float* __restrict__ Y1,
                                                   const float* __restrict__ Chi,
                                                   unsigned short* __restrict__ Gout) {
  __shared__ float Bs[256][33];
  __shared__ float Wl[32][33];
  int t = threadIdx.x, tc = t & 31, rg = t >> 5;
  int q = blockIdx.x * 32 + tc;
  // build B = [Y | M] columns q0..q0+31
#pragma unroll 1
  for (int rr = 0; rr < 32; ++rr) {
    int r = rg * 32 + rr;
    float v;
    if (q < 256) {
      v = -0.5f * (H[(size_t)r * DIMH + q] + Y1[r * 256 + q] - Y1[q * 256 + r]);
    } else {
      int c = q - 256;
      v = -(H[(size_t)r * DIMH + 256 + c] + Chi[r * 512 + c]);
    }
    Bs[r][tc] = v;
  }
  __syncthreads();
  // ---- forward: for s: U_s = W_s B_s; then B_r -= L_rs U_s (r>s) ----
#pragma unroll 1
  for (int s = 0; s < 8; ++s) {
    for (int idx = t; idx < 1024; idx += 256) Wl[idx >> 5][idx & 31] = Wbuf[s * 1024 + idx];
    __syncthreads();
    float ua[4] = {0.f, 0.f, 0.f, 0.f};
#pragma unroll
    for (int k = 0; k < 32; ++k) {
      float b = Bs[32 * s + k][tc];
#pragma unroll
      for (int rr = 0; rr < 4; ++rr) ua[rr] = fmaf(Wl[rg * 4 + rr][k], b, ua[rr]);
    }
    __syncthreads();
#pragma unroll
    for (int rr = 0; rr < 4; ++rr) Bs[32 * s + rg * 4 + rr][tc] = ua[rr];
    __syncthreads();
#pragma unroll 1
    for (int rb = 32 * (s + 1) + rg * 4; rb < 256; rb += 32) {
      f32x4 acc = {Bs[rb][tc], Bs[rb + 1][tc], Bs[rb + 2][tc], Bs[rb + 3][tc]};
#pragma unroll
      for (int k = 0; k < 32; ++k) {
        float u = Bs[32 * s + k][tc];
        f32x4 lv = *reinterpret_cast<const f32x4*>(&Lg[(32 * s + k) * 256 + rb]);
        acc[0] = fmaf(-lv[0], u, acc[0]);
        acc[1] = fmaf(-lv[1], u, acc[1]);
        acc[2] = fmaf(-lv[2], u, acc[2]);
        acc[3] = fmaf(-lv[3], u, acc[3]);
      }
      Bs[rb][tc] = acc[0]; Bs[rb + 1][tc] = acc[1];
      Bs[rb + 2][tc] = acc[2]; Bs[rb + 3][tc] = acc[3];
    }
    __syncthreads();
  }
  // ---- backward: for s desc: G_s = W_s^T B_s; then B_r -= L_sr^T G_s (r<s) ----
#pragma unroll 1
  for (int s = 7; s >= 0; --s) {
    for (int idx = t; idx < 1024; idx += 256) Wl[idx >> 5][idx & 31] = Wbuf[s * 1024 + idx];
    __syncthreads();
    float ga[4] = {0.f, 0.f, 0.f, 0.f};
#pragma unroll
    for (int k = 0; k < 32; ++k) {
      float b = Bs[32 * s + k][tc];
#pragma unroll
      for (int rr = 0; rr < 4; ++rr) ga[rr] = fmaf(Wl[k][rg * 4 + rr], b, ga[rr]);
    }
    __syncthreads();
#pragma unroll
    for (int rr = 0; rr < 4; ++rr) Bs[32 * s + rg * 4 + rr][tc] = ga[rr];
    __syncthreads();
    if (s > 0) {
#pragma unroll 1
      for (int rb = rg * 4; rb < 32 * s; rb += 32) {
        f32x4 acc = {Bs[rb][tc], Bs[rb + 1][tc], Bs[rb + 2][tc], Bs[rb + 3][tc]};
#pragma unroll
        for (int kq = 0; kq < 8; ++kq) {
          f32x4 l0 = *reinterpret_cast<const f32x4*>(&Lg[(rb + 0) * 256 + 32 * s + 4 * kq]);
          f32x4 l1 = *reinterpret_cast<const f32x4*>(&Lg[(rb + 1) * 256 + 32 * s + 4 * kq]);
          f32x4 l2 = *reinterpret_cast<const f32x4*>(&Lg[(rb + 2) * 256 + 32 * s + 4 * kq]);
          f32x4 l3 = *reinterpret_cast<const f32x4*>(&Lg[(rb + 3) * 256 + 32 * s + 4 * kq]);
#pragma unroll
          for (int e = 0; e < 4; ++e) {
            float g = Bs[32 * s + 4 * kq + e][tc];
            acc[0] = fmaf(-l0[e], g, acc[0]);
            acc[1] = fmaf(-l1[e], g, acc[1]);
            acc[2] = fmaf(-l2[e], g, acc[2]);
            acc[3] = fmaf(-l3[e], g, acc[3]);
          }
        }
        Bs[rb][tc] = acc[0]; Bs[rb + 1][tc] = acc[1];
        Bs[rb + 2][tc] = acc[2]; Bs[rb + 3][tc] = acc[3];
      }
    }
    __syncthreads();
  }
  // write Gout bf16 (row-major [256][768])
#pragma unroll 1
  for (int rr = 0; rr < 32; ++rr) {
    int r = rg * 32 + rr;
    Gout[(size_t)r * DIMH + q] = f2bf(Bs[r][tc]);
  }
}

// ---------------- K6: fused main v3 — [x|w] A-operand entirely in registers ----------------
// (unchanged: counters surface next profile as top dispatch)
#define ACCSTR 33
#define ACC_W 4224
#define DD_W 2048
#define WT_W 2560
#define SMEM_MAIN (4 * (ACC_W + DD_W + WT_W))

__global__ __launch_bounds__(256, 2) void k_main(const float* __restrict__ x,
                                                 const unsigned short* __restrict__ Gin,
                                                 const unsigned short* __restrict__ Gout,
                                                 const float* __restrict__ bv,
                                                 const float* __restrict__ bx,
                                                 float* __restrict__ out) {
  extern __shared__ char smem[];
  int tid = threadIdx.x;
  int wv = tid >> 6, l = tid & 63;
  int lr = l & 15, lq = l >> 4, koff = lq * 8;
  float* accb = (float*)(smem + wv * ACC_W);
  char* ddiag = smem + 4 * ACC_W + wv * DD_W;
  char* wtmp = smem + 4 * ACC_W + 4 * DD_W + wv * WT_W;

  int rowbase = blockIdx.x * 128 + wv * 32;

  bf16x8 frag0[24], frag1[24];
  {
    u16x8 zz = {0, 0, 0, 0, 0, 0, 0, 0};
#pragma unroll
    for (int c = 8; c < 24; ++c) {
      frag0[c] = __builtin_bit_cast(bf16x8, zz);
      frag1[c] = __builtin_bit_cast(bf16x8, zz);
    }
  }
#pragma unroll
  for (int kc = 0; kc < 8; ++kc) {
    const float* xr0 = x + (size_t)(rowbase + lr) * 256 + koff + kc * 32;
    const float* xr1 = x + (size_t)(rowbase + 16 + lr) * 256 + koff + kc * 32;
    f32x4 a0 = *reinterpret_cast<const f32x4*>(xr0);
    f32x4 a1 = *reinterpret_cast<const f32x4*>(xr0 + 4);
    f32x4 b0 = *reinterpret_cast<const f32x4*>(xr1);
    f32x4 b1 = *reinterpret_cast<const f32x4*>(xr1 + 4);
    u16x8 u0, u1;
#pragma unroll
    for (int e = 0; e < 4; ++e) {
      u0[e] = f2bf(a0[e]); u0[4 + e] = f2bf(a1[e]);
      u1[e] = f2bf(b0[e]); u1[4 + e] = f2bf(b1[e]);
    }
    frag0[kc] = __builtin_bit_cast(bf16x8, u0);
    frag1[kc] = __builtin_bit_cast(bf16x8, u1);
  }

  f32x4 z = {0.f, 0.f, 0.f, 0.f};

#pragma unroll 1
  for (int b = 0; b < 16; ++b) {
#pragma unroll
    for (int t = 0; t < 2; ++t) {
      int row = t * 16 + (l >> 2);
      const unsigned short* src =
          Gin + (size_t)(32 * b + row) * DIMH + 256 + 32 * b + (l & 3) * 8;
      u16x8 v = *reinterpret_cast<const u16x8*>(src);
      *reinterpret_cast<u16x8*>(ddiag + t * 1024 + l * 16) = v;
    }

    f32x4 a00 = z, a01 = z, a10 = z, a11 = z;
    const unsigned short* gb0 = Gin + (size_t)(32 * b + lr) * DIMH + koff;
    const unsigned short* gb1 = gb0 + 16 * DIMH;
#pragma unroll
    for (int g = 0; g < 6; ++g) {
      if (g * 4 < 8 + b) {
#pragma unroll
        for (int cc = 0; cc < 4; ++cc) {
          int c = g * 4 + cc;
          bf16x8 bb0 = ld8(gb0 + c * 32);
          bf16x8 bb1 = ld8(gb1 + c * 32);
          a00 = mfma16(frag0[c], bb0, a00);
          a01 = mfma16(frag0[c], bb1, a01);
          a10 = mfma16(frag1[c], bb0, a10);
          a11 = mfma16(frag1[c], bb1, a11);
        }
      }
    }

    float bv0 = bv[32 * b + lr], bv1 = bv[32 * b + 16 + lr];
#pragma unroll
    for (int r = 0; r < 4; ++r) {
      accb[(lq * 4 + r) * ACCSTR + lr] = a00[r] + bv0;
      accb[(lq * 4 + r) * ACCSTR + 16 + lr] = a01[r] + bv1;
      accb[(16 + lq * 4 + r) * ACCSTR + lr] = a10[r] + bv0;
      accb[(16 + lq * 4 + r) * ACCSTR + 16 + lr] = a11[r] + bv1;
    }

    if (l < 32) {
      const unsigned int* dd = (const unsigned int*)ddiag;
      float wf[32];
      unsigned int wpk[16];
#pragma unroll
      for (int i = 0; i < 32; ++i) {
        float p0 = 0.f, p1 = 0.f;
        const unsigned int* ddr = dd + i * 16;
#pragma unroll
        for (int j = 0; j < i; ++j) {
          unsigned int pw = ddr[j >> 1];
          float dj = __uint_as_float((j & 1) ? (pw & 0xffff0000u) : (pw << 16));
          if (j & 1) p1 = fmaf(dj, wf[j], p1);
          else       p0 = fmaf(dj, wf[j], p0);
        }
        float s = accb[l * ACCSTR + i] + p0 + p1;
        s = fminf(fmaxf(s, -12.f), 12.f);
        float e = __expf(2.f * s);
        float w = (e - 1.f) * __builtin_amdgcn_rcpf(e + 1.f);
        wf[i] = w;
        unsigned int hb = (unsigned int)f2bf(w);
        if (i & 1) wpk[i >> 1] |= hb << 16;
        else       wpk[i >> 1] = hb;
      }
      u32x4* wp = (u32x4*)(wtmp + l * 80);
      u32x4 w0 = {wpk[0], wpk[1], wpk[2], wpk[3]};     wp[0] = w0;
      u32x4 w1 = {wpk[4], wpk[5], wpk[6], wpk[7]};     wp[1] = w1;
      u32x4 w2 = {wpk[8], wpk[9], wpk[10], wpk[11]};   wp[2] = w2;
      u32x4 w3 = {wpk[12], wpk[13], wpk[14], wpk[15]}; wp[3] = w3;
    }

    bf16x8 nw0 = ld8((const unsigned short*)(wtmp + lr * 80 + lq * 16));
    bf16x8 nw1 = ld8((const unsigned short*)(wtmp + (16 + lr) * 80 + lq * 16));
#pragma unroll
    for (int j = 0; j < 16; ++j) {
      if (b == j) { frag0[8 + j] = nw0; frag1[8 + j] = nw1; }
    }
  }

#pragma unroll 1
  for (int ct = 0; ct < 16; ++ct) {
    f32x4 o0 = z, o1 = z;
    const unsigned short* gg = Gout + (size_t)(ct * 16 + lr) * DIMH + koff;
#pragma unroll
    for (int c = 0; c < 24; ++c) {
      bf16x8 bb = ld8(gg + c * 32);
      o0 = mfma16(frag0[c], bb, o0);
      o1 = mfma16(frag1[c], bb, o1);
    }
    float bxv = bx[ct * 16 + lr];
#pragma unroll
    for (int r = 0; r < 4; ++r) {
      out[(size_t)(rowbase + lq * 4 + r) * 256 + ct * 16 + lr] = o0[r] + bxv;
      out[(size_t)(rowbase + 16 + lq * 4 + r) * 256 + ct * 16 + lr] = o1[r] + bxv;
    }
  }
}

extern "C" void kernel_launch(void* const* d_in, const int* in_sizes, int n_in,
                              void* d_out, int out_size, void* d_ws, size_t ws_size,
                              hipStream_t stream) {
  const float* x   = (const float*)d_in[1];
  const float* Pst = (const float*)d_in[2];
  const float* Chi = (const float*)d_in[3];
  const float* X   = (const float*)d_in[4];
  const float* Y1  = (const float*)d_in[5];
  const float* bv  = (const float*)d_in[8];
  const float* bx  = (const float*)d_in[9];
  float* out = (float*)d_out;

  char* ws = (char*)d_ws;
  const size_t OFF_H    = 0;
  const size_t OFF_P    = 2359296;
  const size_t OFF_WB   = 2621440;   // 8 x 32 x 32 fp32 = 32 KB (old Pinv slot)
  const size_t OFF_XHI  = 2883584;
  const size_t OFF_XLO  = 4063232;
  const size_t OFF_GIN  = 5242880;
  const size_t OFF_GOUT = 6029312;
  if (ws_size < 6422528) return;

  float* H    = (float*)(ws + OFF_H);
  float* P    = (float*)(ws + OFF_P);   // becomes L (lower, col-major) after k_chol
  float* Wbuf = (float*)(ws + OFF_WB);
  unsigned short* Xhi  = (unsigned short*)(ws + OFF_XHI);
  unsigned short* Xlo  = (unsigned short*)(ws + OFF_XLO);
  unsigned short* Gin  = (unsigned short*)(ws + OFF_GIN);
  unsigned short* Gout = (unsigned short*)(ws + OFF_GOUT);

  k_split<<<2304, 256, 0, stream>>>(X, Xhi, Xlo);
  k_syrkP<<<256, 256, 0, stream>>>(Pst, P);
  k_chol<<<1, 1024, 0, stream>>>(P, Wbuf);
  k_syrkH<<<144, 256, 0, stream>>>(Xhi, Xlo, H);
  dim3 gg(3, 512);
  k_gin<<<gg, 256, 0, stream>>>(H, Chi, Gin);
  k_gsolve<<<24, 256, 0, stream>>>(P, Wbuf, H, Y1, Chi, Gout);
  k_main<<<512, 256, SMEM_MAIN, stream>>>(x, Gin, Gout, bv, bx, out);
}

// Round 8
// 763.701 us; speedup vs baseline: 2.0928x; 1.7490x over previous
//
#include <hip/hip_runtime.h>
#include <cstdint>
#include <cstddef>

#define DIMX 256
#define DIMV 512
#define DIMH 768
#define EPSV 0.05f

typedef __bf16 bf16x8 __attribute__((ext_vector_type(8)));
typedef unsigned short u16x8 __attribute__((ext_vector_type(8)));
typedef unsigned int u32x4 __attribute__((ext_vector_type(4)));
typedef float f32x4 __attribute__((ext_vector_type(4)));

__device__ __forceinline__ unsigned short f2bf(float f) {
  unsigned int u = __float_as_uint(f);
  u += 0x7fffu + ((u >> 16) & 1u);
  return (unsigned short)(u >> 16);
}
__device__ __forceinline__ float bf2f(unsigned short b) {
  return __uint_as_float(((unsigned int)b) << 16);
}
__device__ __forceinline__ bf16x8 ld8(const unsigned short* p) {
  u16x8 u = *reinterpret_cast<const u16x8*>(p);
  return __builtin_bit_cast(bf16x8, u);
}
__device__ __forceinline__ f32x4 mfma16(bf16x8 a, bf16x8 b, f32x4 c) {
  return __builtin_amdgcn_mfma_f32_16x16x32_bf16(a, b, c, 0, 0, 0);
}
__device__ __forceinline__ float rdlane(float v, int lane) {
  return __uint_as_float(
      (unsigned int)__builtin_amdgcn_readlane((int)__float_as_uint(v), lane));
}

// ---------------- K0: split X into bf16 hi/lo for split-MFMA SYRK ----------------
__global__ void k_split(const float* __restrict__ X, unsigned short* __restrict__ Xhi,
                        unsigned short* __restrict__ Xlo) {
  int idx = blockIdx.x * 256 + threadIdx.x;
  if (idx < DIMH * DIMH) {
    float f = X[idx];
    unsigned short h = f2bf(f);
    Xhi[idx] = h;
    Xlo[idx] = f2bf(f - bf2f(h));
  }
}

// ---------------- K1: P = 0.5*Pstar@Pstar^T + eps*I (fp32, direct) ----------------
__global__ void k_syrkP(const float* __restrict__ A, float* __restrict__ P) {
  int bi = blockIdx.x >> 4, bj = blockIdx.x & 15;
  int ty = threadIdx.x >> 4, tx = threadIdx.x & 15;
  int i = bi * 16 + ty, j = bj * 16 + tx;
  const f32x4* ra = reinterpret_cast<const f32x4*>(A + (size_t)i * DIMX);
  const f32x4* rb = reinterpret_cast<const f32x4*>(A + (size_t)j * DIMX);
  float s = 0.f;
  for (int k = 0; k < 64; ++k) {
    f32x4 a = ra[k], b = rb[k];
    s = fmaf(a[0], b[0], s); s = fmaf(a[1], b[1], s);
    s = fmaf(a[2], b[2], s); s = fmaf(a[3], b[3], s);
  }
  P[(size_t)i * DIMX + j] = 0.5f * s + (i == j ? EPSV : 0.f);
}

// ---------------- K2: H = X@X^T + eps*I via bf16x2 split MFMA ----------------
__global__ __launch_bounds__(256) void k_syrkH(const unsigned short* __restrict__ Xhi,
                                               const unsigned short* __restrict__ Xlo,
                                               float* __restrict__ H) {
  int bx = blockIdx.x % 12, by = blockIdx.x / 12;
  int i0 = by * 64, j0 = bx * 64;
  int l = threadIdx.x & 63, wv = threadIdx.x >> 6;
  int lr = l & 15, lq = l >> 4;
  int koff = lq * 8;
  int arow = i0 + wv * 16 + lr;
  f32x4 z = {0.f, 0.f, 0.f, 0.f};
  f32x4 acc[4] = {z, z, z, z};
  for (int pass = 0; pass < 3; ++pass) {
    const unsigned short* Xa = (pass == 2) ? Xlo : Xhi;
    const unsigned short* Xb = (pass == 1) ? Xlo : Xhi;
    for (int kc = 0; kc < 24; ++kc) {
      bf16x8 a = ld8(&Xa[(size_t)arow * DIMH + kc * 32 + koff]);
#pragma unroll
      for (int ct = 0; ct < 4; ++ct) {
        bf16x8 b = ld8(&Xb[(size_t)(j0 + ct * 16 + lr) * DIMH + kc * 32 + koff]);
        acc[ct] = mfma16(a, b, acc[ct]);
      }
    }
  }
#pragma unroll
  for (int ct = 0; ct < 4; ++ct)
#pragma unroll
    for (int r = 0; r < 4; ++r) {
      int i = i0 + wv * 16 + lq * 4 + r;
      int j = j0 + ct * 16 + lr;
      H[(size_t)i * DIMH + j] = acc[ct][r] + (i == j ? EPSV : 0.f);
    }
}

// ---------------- K3: blocked Cholesky — 256 THREADS (round-8 fix) ----------------
// Round-7 post-mortem: 1024-thread blocks are VGPR-capped at 64 by hipcc (seen rounds
// 3/5/7); the wave0 serial section needs ~90 -> spilled, 730us. 256-thread blocks get
// 128+ (round 6). Same readlane-serial structure; throughput phases grid-stride at 256.
__global__ __launch_bounds__(256, 1) void k_chol(float* __restrict__ A,
                                                 float* __restrict__ Wbuf) {
  __shared__ float Wl[32][33];    // W row-major: Wl[r][k] = W[r][k]
  __shared__ float T[32][232];    // T[j][rloc] = L21[rloc][j]
  int t = threadIdx.x;
  int wv = t >> 6, l = t & 63;
#pragma unroll 1
  for (int s = 0; s < 8; ++s) {
    int K = 32 * s;
    int R32 = 256 - K - 32;  // trailing rows (224,192,...,0)
    if (wv == 0) {
      int li = l & 31;
      float d[32];
#pragma unroll
      for (int j = 0; j < 32; ++j) d[j] = A[(K + j) * 256 + K + li];
      // pass A: Cholesky, lane i = row i (readlane broadcasts, no barriers/LDS)
#pragma unroll
      for (int k = 0; k < 32; ++k) {
        float dkk = rdlane(d[k], k);
        float ip = rsqrtf(dkk);
        d[k] *= ip;
#pragma unroll
        for (int j = k + 1; j < 32; ++j) {
          float ljk = rdlane(d[k], j);
          d[j] = fmaf(-ljk, d[k], d[j]);
        }
      }
      // pass B: W = Ld^{-1}, lane j = column j. wcol[k] = W[k][j].
      float wcol[32];
#pragma unroll
      for (int i = 0; i < 32; ++i) {
        float Lii = rdlane(d[i], i);
        float ipi = 1.0f / Lii;
        float acc = (li == i) ? 1.0f : 0.0f;
#pragma unroll
        for (int k = 0; k < i; ++k) {
          float Lik = rdlane(d[k], i);
          acc = fmaf(-Lik, wcol[k], acc);
        }
        wcol[i] = acc * ipi;
      }
      if (l < 32) {
#pragma unroll
        for (int k = 0; k < 32; ++k) {
          Wl[k][l] = wcol[k];
          Wbuf[s * 1024 + k * 32 + l] = wcol[k];
        }
      }
    }
    __syncthreads();
    if (R32 > 0) {
      // TRSM: L21[r][j] = sum_k A21[r][k] * W[j][k]  -> into LDS T
      int nrt = R32 >> 2;
      for (int u = t; u < nrt * 8; u += 256) {
        int rt = u >> 3, jg = u & 7;
        int r = K + 32 + rt * 4;
        int j0 = jg * 4;
        f32x4 z4 = {0.f, 0.f, 0.f, 0.f};
        f32x4 acc[4] = {z4, z4, z4, z4};
#pragma unroll
        for (int k = 0; k < 32; ++k) {
          f32x4 av = *reinterpret_cast<const f32x4*>(&A[(K + k) * 256 + r]);
#pragma unroll
          for (int jj = 0; jj < 4; ++jj) {
            float w = Wl[j0 + jj][k];
            acc[jj][0] = fmaf(av[0], w, acc[jj][0]);
            acc[jj][1] = fmaf(av[1], w, acc[jj][1]);
            acc[jj][2] = fmaf(av[2], w, acc[jj][2]);
            acc[jj][3] = fmaf(av[3], w, acc[jj][3]);
          }
        }
#pragma unroll
        for (int jj = 0; jj < 4; ++jj)
          *reinterpret_cast<f32x4*>(&T[j0 + jj][rt * 4]) = acc[jj];
      }
      __syncthreads();
      // copy T -> global A21, coalesced per column (t*4 covers R32<=224)
#pragma unroll 1
      for (int j = 0; j < 32; ++j) {
        int rl = t << 2;
        if (rl < R32)
          *reinterpret_cast<f32x4*>(&A[(K + j) * 256 + K + 32 + rl]) =
              *reinterpret_cast<const f32x4*>(&T[j][rl]);
      }
      // SYRK: A22 -= L21 L21^T, lower 4x4 tiles
      int T4 = R32 >> 2;
      int ntile = T4 * (T4 + 1) / 2;
      for (int idx = t; idx < ntile; idx += 256) {
        int ti = (int)((sqrtf(8.0f * (float)idx + 1.0f) - 1.0f) * 0.5f);
        while ((ti + 1) * (ti + 2) / 2 <= idx) ++ti;
        while (ti * (ti + 1) / 2 > idx) --ti;
        int tj = idx - ti * (ti + 1) / 2;
        int gi = K + 32 + 4 * ti, gj = K + 32 + 4 * tj;
        f32x4 acc[4];
#pragma unroll
        for (int jj = 0; jj < 4; ++jj)
          acc[jj] = *reinterpret_cast<const f32x4*>(&A[(gj + jj) * 256 + gi]);
#pragma unroll
        for (int k = 0; k < 32; ++k) {
          f32x4 av = *reinterpret_cast<const f32x4*>(&T[k][4 * ti]);
          f32x4 bv = *reinterpret_cast<const f32x4*>(&T[k][4 * tj]);
#pragma unroll
          for (int jj = 0; jj < 4; ++jj) {
            acc[jj][0] = fmaf(-av[0], bv[jj], acc[jj][0]);
            acc[jj][1] = fmaf(-av[1], bv[jj], acc[jj][1]);
            acc[jj][2] = fmaf(-av[2], bv[jj], acc[jj][2]);
            acc[jj][3] = fmaf(-av[3], bv[jj], acc[jj][3]);
          }
        }
#pragma unroll
        for (int jj = 0; jj < 4; ++jj)
          *reinterpret_cast<f32x4*>(&A[(gj + jj) * 256 + gi]) = acc[jj];
      }
    }
    __syncthreads();
  }
}

// ---------------- K4: Gin[c][q] = [C1 | D11] as bf16 ----------------
__global__ void k_gin(const float* __restrict__ H, const float* __restrict__ Chi,
                      unsigned short* __restrict__ Gin) {
  int q = blockIdx.x * 256 + threadIdx.x;
  int c = blockIdx.y;
  float rlam = 2.f / H[(size_t)(256 + c) * DIMH + 256 + c];
  float v;
  if (q < 256) {
    v = Chi[(size_t)q * DIMV + c] * rlam;
  } else {
    int j = q - 256;
    v = (j < c) ? -H[(size_t)(256 + c) * DIMH + 256 + j] * rlam : 0.f;
  }
  Gin[(size_t)c * DIMH + q] = f2bf(v);
}

// ---------------- K5: Gout = P^{-1}[Y|M] via BLOCK substitution (GEMM-only) --------
__global__ __launch_bounds__(256, 2) void k_gsolve(const float* __restrict__ Lg,
                                                   const float* __restrict__ Wbuf,
                                                   const float* __restrict__ H,
                                                   const float* __restrict__ Y1,
                                                   const float* __restrict__ Chi,
                                                   unsigned short* __restrict__ Gout) {
  __shared__ float Bs[256][33];
  __shared__ float Wl[32][33];
  int t = threadIdx.x, tc = t & 31, rg = t >> 5;
  int q = blockIdx.x * 32 + tc;
#pragma unroll 1
  for (int rr = 0; rr < 32; ++rr) {
    int r = rg * 32 + rr;
    float v;
    if (q < 256) {
      v = -0.5f * (H[(size_t)r * DIMH + q] + Y1[r * 256 + q] - Y1[q * 256 + r]);
    } else {
      int c = q - 256;
      v = -(H[(size_t)r * DIMH + 256 + c] + Chi[r * 512 + c]);
    }
    Bs[r][tc] = v;
  }
  __syncthreads();
  // forward
#pragma unroll 1
  for (int s = 0; s < 8; ++s) {
    for (int idx = t; idx < 1024; idx += 256) Wl[idx >> 5][idx & 31] = Wbuf[s * 1024 + idx];
    __syncthreads();
    float ua[4] = {0.f, 0.f, 0.f, 0.f};
#pragma unroll
    for (int k = 0; k < 32; ++k) {
      float b = Bs[32 * s + k][tc];
#pragma unroll
      for (int rr = 0; rr < 4; ++rr) ua[rr] = fmaf(Wl[rg * 4 + rr][k], b, ua[rr]);
    }
    __syncthreads();
#pragma unroll
    for (int rr = 0; rr < 4; ++rr) Bs[32 * s + rg * 4 + rr][tc] = ua[rr];
    __syncthreads();
#pragma unroll 1
    for (int rb = 32 * (s + 1) + rg * 4; rb < 256; rb += 32) {
      f32x4 acc = {Bs[rb][tc], Bs[rb + 1][tc], Bs[rb + 2][tc], Bs[rb + 3][tc]};
#pragma unroll
      for (int k = 0; k < 32; ++k) {
        float u = Bs[32 * s + k][tc];
        f32x4 lv = *reinterpret_cast<const f32x4*>(&Lg[(32 * s + k) * 256 + rb]);
        acc[0] = fmaf(-lv[0], u, acc[0]);
        acc[1] = fmaf(-lv[1], u, acc[1]);
        acc[2] = fmaf(-lv[2], u, acc[2]);
        acc[3] = fmaf(-lv[3], u, acc[3]);
      }
      Bs[rb][tc] = acc[0]; Bs[rb + 1][tc] = acc[1];
      Bs[rb + 2][tc] = acc[2]; Bs[rb + 3][tc] = acc[3];
    }
    __syncthreads();
  }
  // backward
#pragma unroll 1
  for (int s = 7; s >= 0; --s) {
    for (int idx = t; idx < 1024; idx += 256) Wl[idx >> 5][idx & 31] = Wbuf[s * 1024 + idx];
    __syncthreads();
    float ga[4] = {0.f, 0.f, 0.f, 0.f};
#pragma unroll
    for (int k = 0; k < 32; ++k) {
      float b = Bs[32 * s + k][tc];
#pragma unroll
      for (int rr = 0; rr < 4; ++rr) ga[rr] = fmaf(Wl[k][rg * 4 + rr], b, ga[rr]);
    }
    __syncthreads();
#pragma unroll
    for (int rr = 0; rr < 4; ++rr) Bs[32 * s + rg * 4 + rr][tc] = ga[rr];
    __syncthreads();
    if (s > 0) {
#pragma unroll 1
      for (int rb = rg * 4; rb < 32 * s; rb += 32) {
        f32x4 acc = {Bs[rb][tc], Bs[rb + 1][tc], Bs[rb + 2][tc], Bs[rb + 3][tc]};
#pragma unroll
        for (int kq = 0; kq < 8; ++kq) {
          f32x4 l0 = *reinterpret_cast<const f32x4*>(&Lg[(rb + 0) * 256 + 32 * s + 4 * kq]);
          f32x4 l1 = *reinterpret_cast<const f32x4*>(&Lg[(rb + 1) * 256 + 32 * s + 4 * kq]);
          f32x4 l2 = *reinterpret_cast<const f32x4*>(&Lg[(rb + 2) * 256 + 32 * s + 4 * kq]);
          f32x4 l3 = *reinterpret_cast<const f32x4*>(&Lg[(rb + 3) * 256 + 32 * s + 4 * kq]);
#pragma unroll
          for (int e = 0; e < 4; ++e) {
            float g = Bs[32 * s + 4 * kq + e][tc];
            acc[0] = fmaf(-l0[e], g, acc[0]);
            acc[1] = fmaf(-l1[e], g, acc[1]);
            acc[2] = fmaf(-l2[e], g, acc[2]);
            acc[3] = fmaf(-l3[e], g, acc[3]);
          }
        }
        Bs[rb][tc] = acc[0]; Bs[rb + 1][tc] = acc[1];
        Bs[rb + 2][tc] = acc[2]; Bs[rb + 3][tc] = acc[3];
      }
    }
    __syncthreads();
  }
#pragma unroll 1
  for (int rr = 0; rr < 32; ++rr) {
    int r = rg * 32 + rr;
    Gout[(size_t)r * DIMH + q] = f2bf(Bs[r][tc]);
  }
}

// ---------------- K6: fused main v3 — [x|w] A-operand entirely in registers ----------------
#define ACCSTR 33
#define ACC_W 4224
#define DD_W 2048
#define WT_W 2560
#define SMEM_MAIN (4 * (ACC_W + DD_W + WT_W))

__global__ __launch_bounds__(256, 2) void k_main(const float* __restrict__ x,
                                                 const unsigned short* __restrict__ Gin,
                                                 const unsigned short* __restrict__ Gout,
                                                 const float* __restrict__ bv,
                                                 const float* __restrict__ bx,
                                                 float* __restrict__ out) {
  extern __shared__ char smem[];
  int tid = threadIdx.x;
  int wv = tid >> 6, l = tid & 63;
  int lr = l & 15, lq = l >> 4, koff = lq * 8;
  float* accb = (float*)(smem + wv * ACC_W);
  char* ddiag = smem + 4 * ACC_W + wv * DD_W;
  char* wtmp = smem + 4 * ACC_W + 4 * DD_W + wv * WT_W;

  int rowbase = blockIdx.x * 128 + wv * 32;

  bf16x8 frag0[24], frag1[24];
  {
    u16x8 zz = {0, 0, 0, 0, 0, 0, 0, 0};
#pragma unroll
    for (int c = 8; c < 24; ++c) {
      frag0[c] = __builtin_bit_cast(bf16x8, zz);
      frag1[c] = __builtin_bit_cast(bf16x8, zz);
    }
  }
#pragma unroll
  for (int kc = 0; kc < 8; ++kc) {
    const float* xr0 = x + (size_t)(rowbase + lr) * 256 + koff + kc * 32;
    const float* xr1 = x + (size_t)(rowbase + 16 + lr) * 256 + koff + kc * 32;
    f32x4 a0 = *reinterpret_cast<const f32x4*>(xr0);
    f32x4 a1 = *reinterpret_cast<const f32x4*>(xr0 + 4);
    f32x4 b0 = *reinterpret_cast<const f32x4*>(xr1);
    f32x4 b1 = *reinterpret_cast<const f32x4*>(xr1 + 4);
    u16x8 u0, u1;
#pragma unroll
    for (int e = 0; e < 4; ++e) {
      u0[e] = f2bf(a0[e]); u0[4 + e] = f2bf(a1[e]);
      u1[e] = f2bf(b0[e]); u1[4 + e] = f2bf(b1[e]);
    }
    frag0[kc] = __builtin_bit_cast(bf16x8, u0);
    frag1[kc] = __builtin_bit_cast(bf16x8, u1);
  }

  f32x4 z = {0.f, 0.f, 0.f, 0.f};

#pragma unroll 1
  for (int b = 0; b < 16; ++b) {
#pragma unroll
    for (int t = 0; t < 2; ++t) {
      int row = t * 16 + (l >> 2);
      const unsigned short* src =
          Gin + (size_t)(32 * b + row) * DIMH + 256 + 32 * b + (l & 3) * 8;
      u16x8 v = *reinterpret_cast<const u16x8*>(src);
      *reinterpret_cast<u16x8*>(ddiag + t * 1024 + l * 16) = v;
    }

    f32x4 a00 = z, a01 = z, a10 = z, a11 = z;
    const unsigned short* gb0 = Gin + (size_t)(32 * b + lr) * DIMH + koff;
    const unsigned short* gb1 = gb0 + 16 * DIMH;
#pragma unroll
    for (int g = 0; g < 6; ++g) {
      if (g * 4 < 8 + b) {
#pragma unroll
        for (int cc = 0; cc < 4; ++cc) {
          int c = g * 4 + cc;
          bf16x8 bb0 = ld8(gb0 + c * 32);
          bf16x8 bb1 = ld8(gb1 + c * 32);
          a00 = mfma16(frag0[c], bb0, a00);
          a01 = mfma16(frag0[c], bb1, a01);
          a10 = mfma16(frag1[c], bb0, a10);
          a11 = mfma16(frag1[c], bb1, a11);
        }
      }
    }

    float bv0 = bv[32 * b + lr], bv1 = bv[32 * b + 16 + lr];
#pragma unroll
    for (int r = 0; r < 4; ++r) {
      accb[(lq * 4 + r) * ACCSTR + lr] = a00[r] + bv0;
      accb[(lq * 4 + r) * ACCSTR + 16 + lr] = a01[r] + bv1;
      accb[(16 + lq * 4 + r) * ACCSTR + lr] = a10[r] + bv0;
      accb[(16 + lq * 4 + r) * ACCSTR + 16 + lr] = a11[r] + bv1;
    }

    if (l < 32) {
      const unsigned int* dd = (const unsigned int*)ddiag;
      float wf[32];
      unsigned int wpk[16];
#pragma unroll
      for (int i = 0; i < 32; ++i) {
        float p0 = 0.f, p1 = 0.f;
        const unsigned int* ddr = dd + i * 16;
#pragma unroll
        for (int j = 0; j < i; ++j) {
          unsigned int pw = ddr[j >> 1];
          float dj = __uint_as_float((j & 1) ? (pw & 0xffff0000u) : (pw << 16));
          if (j & 1) p1 = fmaf(dj, wf[j], p1);
          else       p0 = fmaf(dj, wf[j], p0);
        }
        float s = accb[l * ACCSTR + i] + p0 + p1;
        s = fminf(fmaxf(s, -12.f), 12.f);
        float e = __expf(2.f * s);
        float w = (e - 1.f) * __builtin_amdgcn_rcpf(e + 1.f);
        wf[i] = w;
        unsigned int hb = (unsigned int)f2bf(w);
        if (i & 1) wpk[i >> 1] |= hb << 16;
        else       wpk[i >> 1] = hb;
      }
      u32x4* wp = (u32x4*)(wtmp + l * 80);
      u32x4 w0 = {wpk[0], wpk[1], wpk[2], wpk[3]};     wp[0] = w0;
      u32x4 w1 = {wpk[4], wpk[5], wpk[6], wpk[7]};     wp[1] = w1;
      u32x4 w2 = {wpk[8], wpk[9], wpk[10], wpk[11]};   wp[2] = w2;
      u32x4 w3 = {wpk[12], wpk[13], wpk[14], wpk[15]}; wp[3] = w3;
    }

    bf16x8 nw0 = ld8((const unsigned short*)(wtmp + lr * 80 + lq * 16));
    bf16x8 nw1 = ld8((const unsigned short*)(wtmp + (16 + lr) * 80 + lq * 16));
#pragma unroll
    for (int j = 0; j < 16; ++j) {
      if (b == j) { frag0[8 + j] = nw0; frag1[8 + j] = nw1; }
    }
  }

#pragma unroll 1
  for (int ct = 0; ct < 16; ++ct) {
    f32x4 o0 = z, o1 = z;
    const unsigned short* gg = Gout + (size_t)(ct * 16 + lr) * DIMH + koff;
#pragma unroll
    for (int c = 0; c < 24; ++c) {
      bf16x8 bb = ld8(gg + c * 32);
      o0 = mfma16(frag0[c], bb, o0);
      o1 = mfma16(frag1[c], bb, o1);
    }
    float bxv = bx[ct * 16 + lr];
#pragma unroll
    for (int r = 0; r < 4; ++r) {
      out[(size_t)(rowbase + lq * 4 + r) * 256 + ct * 16 + lr] = o0[r] + bxv;
      out[(size_t)(rowbase + 16 + lq * 4 + r) * 256 + ct * 16 + lr] = o1[r] + bxv;
    }
  }
}

extern "C" void kernel_launch(void* const* d_in, const int* in_sizes, int n_in,
                              void* d_out, int out_size, void* d_ws, size_t ws_size,
                              hipStream_t stream) {
  const float* x   = (const float*)d_in[1];
  const float* Pst = (const float*)d_in[2];
  const float* Chi = (const float*)d_in[3];
  const float* X   = (const float*)d_in[4];
  const float* Y1  = (const float*)d_in[5];
  const float* bv  = (const float*)d_in[8];
  const float* bx  = (const float*)d_in[9];
  float* out = (float*)d_out;

  char* ws = (char*)d_ws;
  const size_t OFF_H    = 0;
  const size_t OFF_P    = 2359296;
  const size_t OFF_WB   = 2621440;
  const size_t OFF_XHI  = 2883584;
  const size_t OFF_XLO  = 4063232;
  const size_t OFF_GIN  = 5242880;
  const size_t OFF_GOUT = 6029312;
  if (ws_size < 6422528) return;

  float* H    = (float*)(ws + OFF_H);
  float* P    = (float*)(ws + OFF_P);   // becomes L (lower, col-major) after k_chol
  float* Wbuf = (float*)(ws + OFF_WB);
  unsigned short* Xhi  = (unsigned short*)(ws + OFF_XHI);
  unsigned short* Xlo  = (unsigned short*)(ws + OFF_XLO);
  unsigned short* Gin  = (unsigned short*)(ws + OFF_GIN);
  unsigned short* Gout = (unsigned short*)(ws + OFF_GOUT);

  k_split<<<2304, 256, 0, stream>>>(X, Xhi, Xlo);
  k_syrkP<<<256, 256, 0, stream>>>(Pst, P);
  k_chol<<<1, 256, 0, stream>>>(P, Wbuf);
  k_syrkH<<<144, 256, 0, stream>>>(Xhi, Xlo, H);
  dim3 gg(3, 512);
  k_gin<<<gg, 256, 0, stream>>>(H, Chi, Gin);
  k_gsolve<<<24, 256, 0, stream>>>(P, Wbuf, H, Y1, Chi, Gout);
  k_main<<<512, 256, SMEM_MAIN, stream>>>(x, Gin, Gout, bv, bx, out);
}